// Round 11
// baseline (187.921 us; speedup 1.0000x reference)
//
#include <hip/hip_runtime.h>
#include <hip/hip_bf16.h>

// GConv: out = relu( Agg(support) + x@loop_W + bias )
// R10: 3 dispatches.
//  D1 {histscan(1 block, LDS hist+scan) | transpose W/LW | cvt X->bf16}
//  D2 {dual GEMM via global_load_lds | edge scatter}
//  D3 agg: wave=(row,batch) ushort4 lanes + LDS-staged edge lists.
// Lesson from R9: agg is issue/latency-bound, NOT traffic-bound — optimize
// instructions and dependent loads, not bytes.

#define NN 10000
#define DK 256
#define DO 256
#define MT 20000      // B*N rows
#define ECAP 128      // staged edges per row (deg mean 32; fallback beyond)

typedef short short8 __attribute__((ext_vector_type(8)));
typedef float f32x4 __attribute__((ext_vector_type(4)));

#define GLOAD_LDS(G, L) __builtin_amdgcn_global_load_lds(                 \
    (const __attribute__((address_space(1))) void*)(G),                   \
    (__attribute__((address_space(3))) void*)(L), 16, 0, 0)

__device__ inline unsigned short f2bf(float f) {
    unsigned int u = __float_as_uint(f);
    u = (u + 0x7FFFu + ((u >> 16) & 1u)) >> 16;   // round-nearest-even
    return (unsigned short)u;
}
__device__ inline float bf2f(unsigned short s) {
    return __uint_as_float(((unsigned int)s) << 16);
}

// ---------------- D1: block 0 histscan | blocks [1,33) transpose | rest cvt ----------------
__global__ __launch_bounds__(1024) void prep_kernel(
    const float* __restrict__ X, unsigned short* __restrict__ Xb,
    const float* __restrict__ W, const float* __restrict__ LW,
    unsigned short* __restrict__ Wt, unsigned short* __restrict__ LWt,
    const int* __restrict__ rows, int* __restrict__ offsets,
    int* __restrict__ cursor, int E)
{
    __shared__ int lds_cnt[NN];      // 40,000 B
    __shared__ int sums[1024];       //  4,096 B
    __shared__ float tile[64][65];   // 16,640 B
    const int tid = threadIdx.x;
    const int bid = blockIdx.x;

    if (bid == 0) {
        // ---- LDS histogram ----
        for (int i = tid; i < NN; i += 1024) lds_cnt[i] = 0;
        __syncthreads();
        for (int i = tid; i < E; i += 1024) atomicAdd(&lds_cnt[rows[i]], 1);
        __syncthreads();
        // ---- in-block exclusive scan (10 per thread + Hillis-Steele 1024) ----
        int local[10];
        int s = 0;
        const int base = tid * 10;
        #pragma unroll
        for (int q = 0; q < 10; ++q) {
            const int idx = base + q;
            const int c = (idx < NN) ? lds_cnt[idx] : 0;
            local[q] = s;
            s += c;
        }
        sums[tid] = s;
        __syncthreads();
        for (int off = 1; off < 1024; off <<= 1) {
            int u = (tid >= off) ? sums[tid - off] : 0;
            __syncthreads();
            sums[tid] += u;
            __syncthreads();
        }
        const int excl = (tid == 0) ? 0 : sums[tid - 1];
        #pragma unroll
        for (int q = 0; q < 10; ++q) {
            const int idx = base + q;
            if (idx < NN) {
                const int o = excl + local[q];
                offsets[idx] = o;
                cursor[idx]  = o;
            }
        }
        if (tid == 1023) offsets[NN] = sums[1023];   // total = E
    } else if (bid < 33) {
        // ---- transpose+convert one 64x64 tile of W or LW ----
        const int zb = bid - 1;
        const int z = zb >> 4, rem = zb & 15;
        const int k0 = (rem >> 2) * 64, c0 = (rem & 3) * 64;
        const float* src = z ? LW : W;
        unsigned short* dst = z ? LWt : Wt;
        #pragma unroll
        for (int p = 0; p < 4; ++p) {
            const int u = p * 1024 + tid;
            const int i = u >> 6, j = u & 63;
            tile[i][j] = src[(size_t)(k0 + i) * DO + c0 + j];
        }
        __syncthreads();
        #pragma unroll
        for (int p = 0; p < 4; ++p) {
            const int u = p * 1024 + tid;
            const int j = u >> 6, i = u & 63;
            dst[(size_t)(c0 + j) * DK + k0 + i] = f2bf(tile[i][j]);
        }
    } else {
        // ---- cvt X -> bf16, one short8 per thread ----
        const int i = (bid - 33) * 1024 + tid;    // < 640000
        const float4 a = ((const float4*)X)[2 * i];
        const float4 b = ((const float4*)X)[2 * i + 1];
        short8 o;
        o[0] = (short)f2bf(a.x); o[1] = (short)f2bf(a.y);
        o[2] = (short)f2bf(a.z); o[3] = (short)f2bf(a.w);
        o[4] = (short)f2bf(b.x); o[5] = (short)f2bf(b.y);
        o[6] = (short)f2bf(b.z); o[7] = (short)f2bf(b.w);
        *(short8*)&Xb[(size_t)i * 8] = o;
    }
}

// ---------------- D2: blocks [0,gemmBlocks) dual GEMM via global_load_lds; rest: scatter ----------------
__global__ __launch_bounds__(256) void main_kernel(
    const unsigned short* __restrict__ Xb, const unsigned short* __restrict__ Wt,
    const unsigned short* __restrict__ LWt, const float* __restrict__ bias,
    unsigned short* __restrict__ sup, float* __restrict__ outv,
    const int* __restrict__ rows, const int* __restrict__ cols,
    const float* __restrict__ vals, int* __restrict__ cursor,
    float2* __restrict__ epack, int E, int gemmBlocks)
{
    __shared__ unsigned short Abuf[8 * 64 * 8];
    __shared__ unsigned short BbufW[8 * 64 * 8];
    __shared__ unsigned short BbufL[8 * 64 * 8];

    if ((int)blockIdx.x >= gemmBlocks) {
        const int e = (blockIdx.x - gemmBlocks) * 256 + threadIdx.x;
        if (e < E) {
            const int p = atomicAdd(&cursor[rows[e]], 1);
            epack[p] = make_float2(__int_as_float(cols[e]), vals[e]);
        }
        return;
    }

    const int t = threadIdx.x;
    const int wid = t >> 6, lane = t & 63;
    const int wm = wid >> 1, wn = wid & 1;
    const int m0 = (blockIdx.x >> 2) * 64;
    const int n0 = (blockIdx.x & 3) * 64;

    f32x4 accW[2][2], accL[2][2];
    #pragma unroll
    for (int i = 0; i < 2; ++i)
        #pragma unroll
        for (int j = 0; j < 2; ++j) {
            accW[i][j] = (f32x4){0.f, 0.f, 0.f, 0.f};
            accL[i][j] = (f32x4){0.f, 0.f, 0.f, 0.f};
        }

    for (int k0 = 0; k0 < DK; k0 += 64) {
        #pragma unroll
        for (int c = 0; c < 2; ++c) {
            const int kg = c * 4 + wid;                 // wave-uniform
            const int src_r = lane ^ kg;                // pre-swizzled source
            const size_t aoff = (size_t)(m0 + src_r) * DK + k0 + kg * 8;
            const size_t boff = (size_t)(n0 + src_r) * DK + k0 + kg * 8;
            GLOAD_LDS(&Xb[aoff],  &Abuf[(c * 256 + wid * 64) * 8]);
            GLOAD_LDS(&Wt[boff],  &BbufW[(c * 256 + wid * 64) * 8]);
            GLOAD_LDS(&LWt[boff], &BbufL[(c * 256 + wid * 64) * 8]);
        }
        __syncthreads();
        #pragma unroll
        for (int s = 0; s < 2; ++s) {             // two k=32 substeps
            const int kg = s * 4 + (lane >> 4);
            short8 af[2], bW[2], bL[2];
            #pragma unroll
            for (int i = 0; i < 2; ++i) {
                const int row = wm * 32 + i * 16 + (lane & 15);
                af[i] = *(const short8*)&Abuf[((size_t)kg * 64 + (row ^ kg)) * 8];
            }
            #pragma unroll
            for (int j = 0; j < 2; ++j) {
                const int col = wn * 32 + j * 16 + (lane & 15);
                bW[j] = *(const short8*)&BbufW[((size_t)kg * 64 + (col ^ kg)) * 8];
                bL[j] = *(const short8*)&BbufL[((size_t)kg * 64 + (col ^ kg)) * 8];
            }
            #pragma unroll
            for (int i = 0; i < 2; ++i)
                #pragma unroll
                for (int j = 0; j < 2; ++j) {
                    accW[i][j] = __builtin_amdgcn_mfma_f32_16x16x32_bf16(
                        af[i], bW[j], accW[i][j], 0, 0, 0);
                    accL[i][j] = __builtin_amdgcn_mfma_f32_16x16x32_bf16(
                        af[i], bL[j], accL[i][j], 0, 0, 0);
                }
        }
        __syncthreads();
    }

    const int rbase = m0 + wm * 32;
    const int cbase = n0 + wn * 32;
    #pragma unroll
    for (int i = 0; i < 2; ++i)
        #pragma unroll
        for (int q = 0; q < 4; ++q) {
            const int row = rbase + i * 16 + (lane >> 4) * 4 + q;
            if (row < MT) {
                #pragma unroll
                for (int j = 0; j < 2; ++j) {
                    const int col = cbase + j * 16 + (lane & 15);
                    sup[(size_t)row * DO + col] = f2bf(accW[i][j][q]);
                    outv[(size_t)row * DO + col] = accL[i][j][q] + bias[col];
                }
            }
        }
}

// ---------------- D3: aggregate + ReLU ----------------
// Block = 4 waves = rows {2bid, 2bid+1} x batches. Edge lists for the 2 rows
// staged in LDS (<=ECAP each; wave-uniform global fallback beyond).
__global__ __launch_bounds__(256) void agg_relu(
    const unsigned short* __restrict__ sup, const float2* __restrict__ epack,
    const int* __restrict__ offsets, float* __restrict__ outv)
{
    __shared__ float2 eps[2][ECAP];
    const int bid = blockIdx.x;
    const int tid = threadIdx.x;
    const int r0 = bid * 2;

    const int start0 = offsets[r0];
    const int end0   = offsets[r0 + 1];
    const int end1   = offsets[r0 + 2];
    const int deg0 = end0 - start0, deg1 = end1 - end0;

    {   // stage: threads [0,128) -> row0, [128,256) -> row1
        const int half = tid >> 7;
        const int idx  = tid & (ECAP - 1);
        const int st = half ? end0 : start0;
        const int dg = half ? deg1 : deg0;
        if (idx < dg) eps[half][idx] = epack[st + idx];
    }
    __syncthreads();

    const int wid = tid >> 6, lane = tid & 63;
    const int b = wid & 1, rsel = wid >> 1;
    const int r = r0 + rsel;
    const int start = rsel ? end0 : start0;
    const int deg   = rsel ? deg1 : deg0;
    const int d = lane * 4;
    const size_t supb = (size_t)b * NN * DO + d;

    float a0 = 0.f, a1 = 0.f, a2 = 0.f, a3 = 0.f;
    #pragma unroll 8
    for (int i = 0; i < deg; ++i) {
        const float2 ep = (i < ECAP) ? eps[rsel][i] : epack[start + i];
        const int col = __float_as_int(ep.x);
        const float v = ep.y;
        const uint2 s2 = *(const uint2*)&sup[supb + (size_t)col * DO];
        a0 += v * __uint_as_float(s2.x << 16);
        a1 += v * __uint_as_float(s2.x & 0xFFFF0000u);
        a2 += v * __uint_as_float(s2.y << 16);
        a3 += v * __uint_as_float(s2.y & 0xFFFF0000u);
    }

    float* o = &outv[((size_t)b * NN + r) * DO + d];
    float4 t4 = *(const float4*)o;
    t4.x = fmaxf(t4.x + a0, 0.f); t4.y = fmaxf(t4.y + a1, 0.f);
    t4.z = fmaxf(t4.z + a2, 0.f); t4.w = fmaxf(t4.w + a3, 0.f);
    *(float4*)o = t4;
}

extern "C" void kernel_launch(void* const* d_in, const int* in_sizes, int n_in,
                              void* d_out, int out_size, void* d_ws, size_t ws_size,
                              hipStream_t stream)
{
    const float* x    = (const float*)d_in[0];
    const float* W    = (const float*)d_in[1];
    const float* LW   = (const float*)d_in[2];
    const float* bias = (const float*)d_in[3];
    const float* ev   = (const float*)d_in[4];
    const int*   rows = (const int*)d_in[5];
    const int*   cols = (const int*)d_in[6];
    float* out = (float*)d_out;

    const int E = in_sizes[4];
    const int EB = (E + 255) / 256;
    const int gemmBlocks = ((MT + 63) / 64) * 4;    // 313*4 = 1252

    // workspace layout (Xb padded to 20032 rows; OOB tile-312 reads hit
    // deterministic ws bytes, discarded by the epilogue guard)
    char* wsb = (char*)d_ws;
    unsigned short* Wt    = (unsigned short*)wsb;               // 131,072 B
    unsigned short* LWt   = (unsigned short*)(wsb + 131072);    // 131,072 B
    unsigned short* Xb    = (unsigned short*)(wsb + 262144);    // 10,256,384 B
    unsigned short* supb  = (unsigned short*)(wsb + 10518528);  // 10,240,000 B
    int* offsets = (int*)(wsb + 20758528);                      // 40,064 B (NN+1)
    int* cursor  = (int*)(wsb + 20798592);                      // 40,000 B
    float2* epack = (float2*)(wsb + 20838592);                  // 8*E B

    // D1: histscan (block 0) | transpose (1..32) | cvt (33..657)
    prep_kernel<<<1 + 32 + 625, 1024, 0, stream>>>(
        x, Xb, W, LW, Wt, LWt, rows, offsets, cursor, E);

    // D2: gemm | scatter
    main_kernel<<<gemmBlocks + EB, 256, 0, stream>>>(
        Xb, Wt, LWt, bias, supb, out, rows, cols, ev, cursor, epack, E, gemmBlocks);

    // D3: agg (5000 blocks, 4 waves each)
    agg_relu<<<NN / 2, 256, 0, stream>>>(supb, epack, offsets, out);
}

// Round 12
// 132.811 us; speedup vs baseline: 1.4150x; 1.4150x over previous
//
#include <hip/hip_runtime.h>
#include <hip/hip_bf16.h>

// GConv: out = relu( Agg(support) + x@loop_W + bias )
// R11: revert R10's mega-block histscan (serialized 320k edges on 1 CU ->
//      150us). Back to R8's 5-dispatch chain; keep R10's agg improvements:
//      LDS-staged edge lists + shift/mask bf16 unpack.

#define NN 10000
#define DK 256
#define DO 256
#define MT 20000      // B*N rows
#define SCAN_T 1024
#define SCAN_C 10     // 10240 >= NN
#define CVB 2500      // cvt blocks: 640000 short8 / 256
#define ECAP 128      // staged edges per row (deg mean 32; fallback beyond)

typedef short short8 __attribute__((ext_vector_type(8)));
typedef float f32x4 __attribute__((ext_vector_type(4)));

#define GLOAD_LDS(G, L) __builtin_amdgcn_global_load_lds(                 \
    (const __attribute__((address_space(1))) void*)(G),                   \
    (__attribute__((address_space(3))) void*)(L), 16, 0, 0)

__device__ inline unsigned short f2bf(float f) {
    unsigned int u = __float_as_uint(f);
    u = (u + 0x7FFFu + ((u >> 16) & 1u)) >> 16;   // round-nearest-even
    return (unsigned short)u;
}

// ---------------- prep: [0,CVB) cvt X->bf16 | [CVB,CVB+32) transpose W/LW | rest hist ----------------
__global__ __launch_bounds__(256) void prep_kernel(
    const float* __restrict__ X, unsigned short* __restrict__ Xb,
    const float* __restrict__ W, const float* __restrict__ LW,
    unsigned short* __restrict__ Wt, unsigned short* __restrict__ LWt,
    const int* __restrict__ rows, int* __restrict__ counts, int E)
{
    __shared__ float tile[64][65];
    const int bid = blockIdx.x;
    if (bid < CVB) {
        const int i = bid * 256 + threadIdx.x;   // < 640000 always
        const float4 a = ((const float4*)X)[2 * i];
        const float4 b = ((const float4*)X)[2 * i + 1];
        short8 o;
        o[0] = (short)f2bf(a.x); o[1] = (short)f2bf(a.y);
        o[2] = (short)f2bf(a.z); o[3] = (short)f2bf(a.w);
        o[4] = (short)f2bf(b.x); o[5] = (short)f2bf(b.y);
        o[6] = (short)f2bf(b.z); o[7] = (short)f2bf(b.w);
        *(short8*)&Xb[(size_t)i * 8] = o;
    } else if (bid < CVB + 32) {
        const int zb = bid - CVB;
        const int z = zb >> 4, rem = zb & 15;
        const int k0 = (rem >> 2) * 64, c0 = (rem & 3) * 64;
        const float* src = z ? LW : W;
        unsigned short* dst = z ? LWt : Wt;
        #pragma unroll
        for (int it = 0; it < 16; ++it) {
            const int u = it * 256 + threadIdx.x;
            const int i = u >> 6, j = u & 63;
            tile[i][j] = src[(size_t)(k0 + i) * DO + c0 + j];
        }
        __syncthreads();
        #pragma unroll
        for (int it = 0; it < 16; ++it) {
            const int u = it * 256 + threadIdx.x;
            const int j = u >> 6, i = u & 63;
            dst[(size_t)(c0 + j) * DK + k0 + i] = f2bf(tile[i][j]);
        }
    } else {
        const int e = (bid - CVB - 32) * 256 + threadIdx.x;
        if (e < E) atomicAdd(&counts[rows[e]], 1);
    }
}

// ---------------- scan: exclusive prefix over counts -> offsets (incl. total), cursor ----------------
__global__ __launch_bounds__(SCAN_T) void scan_rows(
    const int* __restrict__ counts, int* __restrict__ offsets,
    int* __restrict__ cursor)
{
    __shared__ int sums[SCAN_T];
    const int t = threadIdx.x;
    int local[SCAN_C];
    int s = 0;
    const int base = t * SCAN_C;
    #pragma unroll
    for (int i = 0; i < SCAN_C; ++i) {
        const int idx = base + i;
        const int c = (idx < NN) ? counts[idx] : 0;
        local[i] = s;
        s += c;
    }
    sums[t] = s;
    __syncthreads();
    for (int off = 1; off < SCAN_T; off <<= 1) {
        int u = (t >= off) ? sums[t - off] : 0;
        __syncthreads();
        sums[t] += u;
        __syncthreads();
    }
    const int excl = (t == 0) ? 0 : sums[t - 1];
    #pragma unroll
    for (int i = 0; i < SCAN_C; ++i) {
        const int idx = base + i;
        if (idx < NN) {
            const int o = excl + local[i];
            offsets[idx] = o;
            cursor[idx]  = o;
        }
    }
    if (t == SCAN_T - 1) offsets[NN] = sums[SCAN_T - 1];   // total = E
}

// ---------------- main: blocks [0,gemmBlocks) dual GEMM via global_load_lds; rest: scatter ----------------
__global__ __launch_bounds__(256) void main_kernel(
    const unsigned short* __restrict__ Xb, const unsigned short* __restrict__ Wt,
    const unsigned short* __restrict__ LWt, const float* __restrict__ bias,
    unsigned short* __restrict__ sup, float* __restrict__ outv,
    const int* __restrict__ rows, const int* __restrict__ cols,
    const float* __restrict__ vals, int* __restrict__ cursor,
    float2* __restrict__ epack, int E, int gemmBlocks)
{
    __shared__ unsigned short Abuf[8 * 64 * 8];
    __shared__ unsigned short BbufW[8 * 64 * 8];
    __shared__ unsigned short BbufL[8 * 64 * 8];

    if ((int)blockIdx.x >= gemmBlocks) {
        const int e = (blockIdx.x - gemmBlocks) * 256 + threadIdx.x;
        if (e < E) {
            const int p = atomicAdd(&cursor[rows[e]], 1);
            epack[p] = make_float2(__int_as_float(cols[e]), vals[e]);
        }
        return;
    }

    const int t = threadIdx.x;
    const int wid = t >> 6, lane = t & 63;
    const int wm = wid >> 1, wn = wid & 1;
    const int m0 = (blockIdx.x >> 2) * 64;
    const int n0 = (blockIdx.x & 3) * 64;

    f32x4 accW[2][2], accL[2][2];
    #pragma unroll
    for (int i = 0; i < 2; ++i)
        #pragma unroll
        for (int j = 0; j < 2; ++j) {
            accW[i][j] = (f32x4){0.f, 0.f, 0.f, 0.f};
            accL[i][j] = (f32x4){0.f, 0.f, 0.f, 0.f};
        }

    for (int k0 = 0; k0 < DK; k0 += 64) {
        #pragma unroll
        for (int c = 0; c < 2; ++c) {
            const int kg = c * 4 + wid;                 // wave-uniform
            const int src_r = lane ^ kg;                // pre-swizzled source
            const size_t aoff = (size_t)(m0 + src_r) * DK + k0 + kg * 8;
            const size_t boff = (size_t)(n0 + src_r) * DK + k0 + kg * 8;
            GLOAD_LDS(&Xb[aoff],  &Abuf[(c * 256 + wid * 64) * 8]);
            GLOAD_LDS(&Wt[boff],  &BbufW[(c * 256 + wid * 64) * 8]);
            GLOAD_LDS(&LWt[boff], &BbufL[(c * 256 + wid * 64) * 8]);
        }
        __syncthreads();
        #pragma unroll
        for (int s = 0; s < 2; ++s) {             // two k=32 substeps
            const int kg = s * 4 + (lane >> 4);
            short8 af[2], bW[2], bL[2];
            #pragma unroll
            for (int i = 0; i < 2; ++i) {
                const int row = wm * 32 + i * 16 + (lane & 15);
                af[i] = *(const short8*)&Abuf[((size_t)kg * 64 + (row ^ kg)) * 8];
            }
            #pragma unroll
            for (int j = 0; j < 2; ++j) {
                const int col = wn * 32 + j * 16 + (lane & 15);
                bW[j] = *(const short8*)&BbufW[((size_t)kg * 64 + (col ^ kg)) * 8];
                bL[j] = *(const short8*)&BbufL[((size_t)kg * 64 + (col ^ kg)) * 8];
            }
            #pragma unroll
            for (int i = 0; i < 2; ++i)
                #pragma unroll
                for (int j = 0; j < 2; ++j) {
                    accW[i][j] = __builtin_amdgcn_mfma_f32_16x16x32_bf16(
                        af[i], bW[j], accW[i][j], 0, 0, 0);
                    accL[i][j] = __builtin_amdgcn_mfma_f32_16x16x32_bf16(
                        af[i], bL[j], accL[i][j], 0, 0, 0);
                }
        }
        __syncthreads();
    }

    const int rbase = m0 + wm * 32;
    const int cbase = n0 + wn * 32;
    #pragma unroll
    for (int i = 0; i < 2; ++i)
        #pragma unroll
        for (int q = 0; q < 4; ++q) {
            const int row = rbase + i * 16 + (lane >> 4) * 4 + q;
            if (row < MT) {
                #pragma unroll
                for (int j = 0; j < 2; ++j) {
                    const int col = cbase + j * 16 + (lane & 15);
                    sup[(size_t)row * DO + col] = f2bf(accW[i][j][q]);
                    outv[(size_t)row * DO + col] = accL[i][j][q] + bias[col];
                }
            }
        }
}

// ---------------- agg + ReLU: block = rows {2bid,2bid+1} x 2 batches ----------------
// Edge lists for the block's 2 rows staged in LDS (<=ECAP; uniform fallback).
__global__ __launch_bounds__(256) void agg_relu(
    const unsigned short* __restrict__ sup, const float2* __restrict__ epack,
    const int* __restrict__ offsets, float* __restrict__ outv)
{
    __shared__ float2 eps[2][ECAP];
    const int bid = blockIdx.x;
    const int tid = threadIdx.x;
    const int r0 = bid * 2;

    const int start0 = offsets[r0];
    const int end0   = offsets[r0 + 1];
    const int end1   = offsets[r0 + 2];
    const int deg0 = end0 - start0, deg1 = end1 - end0;

    {   // stage: threads [0,128) -> row0, [128,256) -> row1
        const int half = tid >> 7;
        const int idx  = tid & (ECAP - 1);
        const int st = half ? end0 : start0;
        const int dg = half ? deg1 : deg0;
        if (idx < dg) eps[half][idx] = epack[st + idx];
    }
    __syncthreads();

    const int wid = tid >> 6, lane = tid & 63;
    const int b = wid & 1, rsel = wid >> 1;
    const int r = r0 + rsel;
    const int start = rsel ? end0 : start0;
    const int deg   = rsel ? deg1 : deg0;
    const int d = lane * 4;
    const size_t supb = (size_t)b * NN * DO + d;

    float a0 = 0.f, a1 = 0.f, a2 = 0.f, a3 = 0.f;
    #pragma unroll 8
    for (int i = 0; i < deg; ++i) {
        const float2 ep = (i < ECAP) ? eps[rsel][i] : epack[start + i];
        const int col = __float_as_int(ep.x);
        const float v = ep.y;
        const uint2 s2 = *(const uint2*)&sup[supb + (size_t)col * DO];
        a0 += v * __uint_as_float(s2.x << 16);
        a1 += v * __uint_as_float(s2.x & 0xFFFF0000u);
        a2 += v * __uint_as_float(s2.y << 16);
        a3 += v * __uint_as_float(s2.y & 0xFFFF0000u);
    }

    float* o = &outv[((size_t)b * NN + r) * DO + d];
    float4 t4 = *(const float4*)o;
    t4.x = fmaxf(t4.x + a0, 0.f); t4.y = fmaxf(t4.y + a1, 0.f);
    t4.z = fmaxf(t4.z + a2, 0.f); t4.w = fmaxf(t4.w + a3, 0.f);
    *(float4*)o = t4;
}

extern "C" void kernel_launch(void* const* d_in, const int* in_sizes, int n_in,
                              void* d_out, int out_size, void* d_ws, size_t ws_size,
                              hipStream_t stream)
{
    const float* x    = (const float*)d_in[0];
    const float* W    = (const float*)d_in[1];
    const float* LW   = (const float*)d_in[2];
    const float* bias = (const float*)d_in[3];
    const float* ev   = (const float*)d_in[4];
    const int*   rows = (const int*)d_in[5];
    const int*   cols = (const int*)d_in[6];
    float* out = (float*)d_out;

    const int E = in_sizes[4];
    const int EB = (E + 255) / 256;
    const int gemmBlocks = ((MT + 63) / 64) * 4;    // 313*4 = 1252

    // workspace layout (Xb padded to 20032 rows; OOB tile-312 reads hit
    // deterministic ws bytes, discarded by the epilogue guard)
    char* wsb = (char*)d_ws;
    unsigned short* Wt    = (unsigned short*)wsb;               // 131,072 B
    unsigned short* LWt   = (unsigned short*)(wsb + 131072);    // 131,072 B
    unsigned short* Xb    = (unsigned short*)(wsb + 262144);    // 10,256,384 B
    unsigned short* supb  = (unsigned short*)(wsb + 10518528);  // 10,240,000 B
    int* counts  = (int*)(wsb + 20758528);                      // 40,000 B
    int* offsets = (int*)(wsb + 20798528);                      // 40,064 B (NN+1)
    int* cursor  = (int*)(wsb + 20838592);                      // 40,000 B
    float2* epack = (float2*)(wsb + 20878592);                  // 8*E B

    hipMemsetAsync(counts, 0, NN * sizeof(int), stream);

    prep_kernel<<<CVB + 32 + EB, 256, 0, stream>>>(
        x, Xb, W, LW, Wt, LWt, rows, counts, E);
    scan_rows<<<1, SCAN_T, 0, stream>>>(counts, offsets, cursor);
    main_kernel<<<gemmBlocks + EB, 256, 0, stream>>>(
        Xb, Wt, LWt, bias, supb, out, rows, cols, ev, cursor, epack, E, gemmBlocks);

    agg_relu<<<NN / 2, 256, 0, stream>>>(supb, epack, offsets, out);
}

// Round 13
// 122.047 us; speedup vs baseline: 1.5397x; 1.0882x over previous
//
#include <hip/hip_runtime.h>
#include <hip/hip_bf16.h>

// GConv: out = relu( Agg(support) + x@loop_W + bias )
// R12: agg rewritten to cut VMEM issue 4x (the R9-proven bottleneck):
//      edge data loaded once per 64 edges into lane registers, broadcast
//      via v_readlane (no memory op); dwordx4 gathers, 2 edges per instr
//      (lane halves); __shfl_xor(32) cross-half reduce. Rest = R8 baseline.

#define NN 10000
#define DK 256
#define DO 256
#define MT 20000      // B*N rows
#define SCAN_T 1024
#define SCAN_C 10     // 10240 >= NN
#define CVB 2500      // cvt blocks: 640000 short8 / 256

typedef short short8 __attribute__((ext_vector_type(8)));
typedef float f32x4 __attribute__((ext_vector_type(4)));

#define GLOAD_LDS(G, L) __builtin_amdgcn_global_load_lds(                 \
    (const __attribute__((address_space(1))) void*)(G),                   \
    (__attribute__((address_space(3))) void*)(L), 16, 0, 0)

__device__ inline unsigned short f2bf(float f) {
    unsigned int u = __float_as_uint(f);
    u = (u + 0x7FFFu + ((u >> 16) & 1u)) >> 16;   // round-nearest-even
    return (unsigned short)u;
}

// ---------------- prep: [0,CVB) cvt X->bf16 | [CVB,CVB+32) transpose W/LW | rest hist ----------------
__global__ __launch_bounds__(256) void prep_kernel(
    const float* __restrict__ X, unsigned short* __restrict__ Xb,
    const float* __restrict__ W, const float* __restrict__ LW,
    unsigned short* __restrict__ Wt, unsigned short* __restrict__ LWt,
    const int* __restrict__ rows, int* __restrict__ counts, int E)
{
    __shared__ float tile[64][65];
    const int bid = blockIdx.x;
    if (bid < CVB) {
        const int i = bid * 256 + threadIdx.x;   // < 640000 always
        const float4 a = ((const float4*)X)[2 * i];
        const float4 b = ((const float4*)X)[2 * i + 1];
        short8 o;
        o[0] = (short)f2bf(a.x); o[1] = (short)f2bf(a.y);
        o[2] = (short)f2bf(a.z); o[3] = (short)f2bf(a.w);
        o[4] = (short)f2bf(b.x); o[5] = (short)f2bf(b.y);
        o[6] = (short)f2bf(b.z); o[7] = (short)f2bf(b.w);
        *(short8*)&Xb[(size_t)i * 8] = o;
    } else if (bid < CVB + 32) {
        const int zb = bid - CVB;
        const int z = zb >> 4, rem = zb & 15;
        const int k0 = (rem >> 2) * 64, c0 = (rem & 3) * 64;
        const float* src = z ? LW : W;
        unsigned short* dst = z ? LWt : Wt;
        #pragma unroll
        for (int it = 0; it < 16; ++it) {
            const int u = it * 256 + threadIdx.x;
            const int i = u >> 6, j = u & 63;
            tile[i][j] = src[(size_t)(k0 + i) * DO + c0 + j];
        }
        __syncthreads();
        #pragma unroll
        for (int it = 0; it < 16; ++it) {
            const int u = it * 256 + threadIdx.x;
            const int j = u >> 6, i = u & 63;
            dst[(size_t)(c0 + j) * DK + k0 + i] = f2bf(tile[i][j]);
        }
    } else {
        const int e = (bid - CVB - 32) * 256 + threadIdx.x;
        if (e < E) atomicAdd(&counts[rows[e]], 1);
    }
}

// ---------------- scan: exclusive prefix over counts -> offsets (incl. total), cursor ----------------
__global__ __launch_bounds__(SCAN_T) void scan_rows(
    const int* __restrict__ counts, int* __restrict__ offsets,
    int* __restrict__ cursor)
{
    __shared__ int sums[SCAN_T];
    const int t = threadIdx.x;
    int local[SCAN_C];
    int s = 0;
    const int base = t * SCAN_C;
    #pragma unroll
    for (int i = 0; i < SCAN_C; ++i) {
        const int idx = base + i;
        const int c = (idx < NN) ? counts[idx] : 0;
        local[i] = s;
        s += c;
    }
    sums[t] = s;
    __syncthreads();
    for (int off = 1; off < SCAN_T; off <<= 1) {
        int u = (t >= off) ? sums[t - off] : 0;
        __syncthreads();
        sums[t] += u;
        __syncthreads();
    }
    const int excl = (t == 0) ? 0 : sums[t - 1];
    #pragma unroll
    for (int i = 0; i < SCAN_C; ++i) {
        const int idx = base + i;
        if (idx < NN) {
            const int o = excl + local[i];
            offsets[idx] = o;
            cursor[idx]  = o;
        }
    }
    if (t == SCAN_T - 1) offsets[NN] = sums[SCAN_T - 1];   // total = E
}

// ---------------- main: blocks [0,gemmBlocks) dual GEMM via global_load_lds; rest: scatter ----------------
__global__ __launch_bounds__(256) void main_kernel(
    const unsigned short* __restrict__ Xb, const unsigned short* __restrict__ Wt,
    const unsigned short* __restrict__ LWt, const float* __restrict__ bias,
    unsigned short* __restrict__ sup, float* __restrict__ outv,
    const int* __restrict__ rows, const int* __restrict__ cols,
    const float* __restrict__ vals, int* __restrict__ cursor,
    float2* __restrict__ epack, int E, int gemmBlocks)
{
    __shared__ unsigned short Abuf[8 * 64 * 8];
    __shared__ unsigned short BbufW[8 * 64 * 8];
    __shared__ unsigned short BbufL[8 * 64 * 8];

    if ((int)blockIdx.x >= gemmBlocks) {
        const int e = (blockIdx.x - gemmBlocks) * 256 + threadIdx.x;
        if (e < E) {
            const int p = atomicAdd(&cursor[rows[e]], 1);
            epack[p] = make_float2(__int_as_float(cols[e]), vals[e]);
        }
        return;
    }

    const int t = threadIdx.x;
    const int wid = t >> 6, lane = t & 63;
    const int wm = wid >> 1, wn = wid & 1;
    const int m0 = (blockIdx.x >> 2) * 64;
    const int n0 = (blockIdx.x & 3) * 64;

    f32x4 accW[2][2], accL[2][2];
    #pragma unroll
    for (int i = 0; i < 2; ++i)
        #pragma unroll
        for (int j = 0; j < 2; ++j) {
            accW[i][j] = (f32x4){0.f, 0.f, 0.f, 0.f};
            accL[i][j] = (f32x4){0.f, 0.f, 0.f, 0.f};
        }

    for (int k0 = 0; k0 < DK; k0 += 64) {
        #pragma unroll
        for (int c = 0; c < 2; ++c) {
            const int kg = c * 4 + wid;                 // wave-uniform
            const int src_r = lane ^ kg;                // pre-swizzled source
            const size_t aoff = (size_t)(m0 + src_r) * DK + k0 + kg * 8;
            const size_t boff = (size_t)(n0 + src_r) * DK + k0 + kg * 8;
            GLOAD_LDS(&Xb[aoff],  &Abuf[(c * 256 + wid * 64) * 8]);
            GLOAD_LDS(&Wt[boff],  &BbufW[(c * 256 + wid * 64) * 8]);
            GLOAD_LDS(&LWt[boff], &BbufL[(c * 256 + wid * 64) * 8]);
        }
        __syncthreads();
        #pragma unroll
        for (int s = 0; s < 2; ++s) {             // two k=32 substeps
            const int kg = s * 4 + (lane >> 4);
            short8 af[2], bW[2], bL[2];
            #pragma unroll
            for (int i = 0; i < 2; ++i) {
                const int row = wm * 32 + i * 16 + (lane & 15);
                af[i] = *(const short8*)&Abuf[((size_t)kg * 64 + (row ^ kg)) * 8];
            }
            #pragma unroll
            for (int j = 0; j < 2; ++j) {
                const int col = wn * 32 + j * 16 + (lane & 15);
                bW[j] = *(const short8*)&BbufW[((size_t)kg * 64 + (col ^ kg)) * 8];
                bL[j] = *(const short8*)&BbufL[((size_t)kg * 64 + (col ^ kg)) * 8];
            }
            #pragma unroll
            for (int i = 0; i < 2; ++i)
                #pragma unroll
                for (int j = 0; j < 2; ++j) {
                    accW[i][j] = __builtin_amdgcn_mfma_f32_16x16x32_bf16(
                        af[i], bW[j], accW[i][j], 0, 0, 0);
                    accL[i][j] = __builtin_amdgcn_mfma_f32_16x16x32_bf16(
                        af[i], bL[j], accL[i][j], 0, 0, 0);
                }
        }
        __syncthreads();
    }

    const int rbase = m0 + wm * 32;
    const int cbase = n0 + wn * 32;
    #pragma unroll
    for (int i = 0; i < 2; ++i)
        #pragma unroll
        for (int q = 0; q < 4; ++q) {
            const int row = rbase + i * 16 + (lane >> 4) * 4 + q;
            if (row < MT) {
                #pragma unroll
                for (int j = 0; j < 2; ++j) {
                    const int col = cbase + j * 16 + (lane & 15);
                    sup[(size_t)row * DO + col] = f2bf(accW[i][j][q]);
                    outv[(size_t)row * DO + col] = accL[i][j][q] + bias[col];
                }
            }
        }
}

// ---------------- agg + ReLU: wave = (row, batch); 2 edges/iter via lane halves ----------------
// Edge (col,val) loaded once per 64-edge chunk into lane registers, broadcast
// per-iteration via v_readlane (uniform index) — no per-edge VMEM for edges.
// Gather: dwordx4, lanes 0-31 edge j (full 512B row), lanes 32-63 edge j+1.
__global__ __launch_bounds__(256) void agg_relu(
    const unsigned short* __restrict__ sup, const float2* __restrict__ epack,
    const int* __restrict__ offsets, float* __restrict__ outv)
{
    const int widx = (blockIdx.x * 256 + threadIdx.x) >> 6;
    if (widx >= 2 * NN) return;
    const int lane = threadIdx.x & 63;
    const int b = widx & 1, r = widx >> 1;
    const int h = lane >> 5;           // half: which edge of the pair
    const int c32 = lane & 31;
    const int start = offsets[r];
    const int deg   = offsets[r + 1] - start;
    const size_t supb = (size_t)b * NN * DO + c32 * 8;

    float a0 = 0.f, a1 = 0.f, a2 = 0.f, a3 = 0.f;
    float a4 = 0.f, a5 = 0.f, a6 = 0.f, a7 = 0.f;

    for (int c0 = 0; c0 < deg; c0 += 64) {
        const int cnt = min(64, deg - c0);
        int   colv = 0;
        float valv = 0.f;
        if (lane < cnt) {
            const float2 e = epack[start + c0 + lane];
            colv = __float_as_int(e.x);
            valv = e.y;
        }
        #pragma unroll 4
        for (int j = 0; j < cnt; j += 2) {
            const int cA  = __builtin_amdgcn_readlane(colv, j);
            const int vAi = __builtin_amdgcn_readlane(__float_as_int(valv), j);
            const bool hasB = (j + 1) < cnt;
            const int cB  = hasB ? __builtin_amdgcn_readlane(colv, j + 1) : cA;
            const int vBi = hasB ? __builtin_amdgcn_readlane(__float_as_int(valv), j + 1) : 0;
            const int   c = h ? cB : cA;
            const float v = __int_as_float(h ? vBi : vAi);
            const uint4 s4 = *(const uint4*)&sup[supb + (size_t)c * DO];
            a0 += v * __uint_as_float(s4.x << 16);
            a1 += v * __uint_as_float(s4.x & 0xFFFF0000u);
            a2 += v * __uint_as_float(s4.y << 16);
            a3 += v * __uint_as_float(s4.y & 0xFFFF0000u);
            a4 += v * __uint_as_float(s4.z << 16);
            a5 += v * __uint_as_float(s4.z & 0xFFFF0000u);
            a6 += v * __uint_as_float(s4.w << 16);
            a7 += v * __uint_as_float(s4.w & 0xFFFF0000u);
        }
    }

    // cross-half reduce: lanes l and l^32 hold partials for the same 8 feats
    a0 += __shfl_xor(a0, 32); a1 += __shfl_xor(a1, 32);
    a2 += __shfl_xor(a2, 32); a3 += __shfl_xor(a3, 32);
    a4 += __shfl_xor(a4, 32); a5 += __shfl_xor(a5, 32);
    a6 += __shfl_xor(a6, 32); a7 += __shfl_xor(a7, 32);

    // half 0 writes feats [c32*8, +4), half 1 writes [c32*8+4, +4)
    const int d = c32 * 8 + h * 4;
    const float w0 = h ? a4 : a0, w1 = h ? a5 : a1;
    const float w2 = h ? a6 : a2, w3 = h ? a7 : a3;
    float* o = &outv[((size_t)b * NN + r) * DO + d];
    float4 t4 = *(const float4*)o;
    t4.x = fmaxf(t4.x + w0, 0.f); t4.y = fmaxf(t4.y + w1, 0.f);
    t4.z = fmaxf(t4.z + w2, 0.f); t4.w = fmaxf(t4.w + w3, 0.f);
    *(float4*)o = t4;
}

extern "C" void kernel_launch(void* const* d_in, const int* in_sizes, int n_in,
                              void* d_out, int out_size, void* d_ws, size_t ws_size,
                              hipStream_t stream)
{
    const float* x    = (const float*)d_in[0];
    const float* W    = (const float*)d_in[1];
    const float* LW   = (const float*)d_in[2];
    const float* bias = (const float*)d_in[3];
    const float* ev   = (const float*)d_in[4];
    const int*   rows = (const int*)d_in[5];
    const int*   cols = (const int*)d_in[6];
    float* out = (float*)d_out;

    const int E = in_sizes[4];
    const int EB = (E + 255) / 256;
    const int gemmBlocks = ((MT + 63) / 64) * 4;    // 313*4 = 1252

    // workspace layout (Xb padded to 20032 rows; OOB tile-312 reads hit
    // deterministic ws bytes, discarded by the epilogue guard)
    char* wsb = (char*)d_ws;
    unsigned short* Wt    = (unsigned short*)wsb;               // 131,072 B
    unsigned short* LWt   = (unsigned short*)(wsb + 131072);    // 131,072 B
    unsigned short* Xb    = (unsigned short*)(wsb + 262144);    // 10,256,384 B
    unsigned short* supb  = (unsigned short*)(wsb + 10518528);  // 10,240,000 B
    int* counts  = (int*)(wsb + 20758528);                      // 40,000 B
    int* offsets = (int*)(wsb + 20798528);                      // 40,064 B (NN+1)
    int* cursor  = (int*)(wsb + 20838592);                      // 40,000 B
    float2* epack = (float2*)(wsb + 20878592);                  // 8*E B

    hipMemsetAsync(counts, 0, NN * sizeof(int), stream);

    prep_kernel<<<CVB + 32 + EB, 256, 0, stream>>>(
        x, Xb, W, LW, Wt, LWt, rows, counts, E);
    scan_rows<<<1, SCAN_T, 0, stream>>>(counts, offsets, cursor);
    main_kernel<<<gemmBlocks + EB, 256, 0, stream>>>(
        Xb, Wt, LWt, bias, supb, out, rows, cols, ev, cursor, epack, E, gemmBlocks);

    agg_relu<<<(2 * NN * 64) / 256, 256, 0, stream>>>(supb, epack, offsets, out);
}